// Round 7
// baseline (365.241 us; speedup 1.0000x reference)
//
#include <hip/hip_runtime.h>

// B=32768, K=64, D=64, GAIN=1.0
#define LOG_2PI 1.8378770664093453f
#define LOG2E   1.4426950408889634f

typedef __attribute__((ext_vector_type(8))) short  short8;   // 8 x bf16
typedef __attribute__((ext_vector_type(4))) float  float4_;
typedef __attribute__((ext_vector_type(2))) unsigned int uint2_;

__device__ __forceinline__ unsigned short f2bf(float f) {
  unsigned u = __builtin_bit_cast(unsigned, f);
  u += 0x7fffu + ((u >> 16) & 1u);   // RNE
  return (unsigned short)(u >> 16);
}
__device__ __forceinline__ float hi2f(unsigned u) {        // bf16 in high half
  return __builtin_bit_cast(float, u & 0xffff0000u);
}
__device__ __forceinline__ float lo2f(unsigned u) {        // bf16 in low half
  return __builtin_bit_cast(float, u << 16);
}
template <int CTRL>
__device__ __forceinline__ float dpp_add(float v) {
  int t = __builtin_amdgcn_mov_dpp(__builtin_bit_cast(int, v), CTRL, 0xf, 0xf, true);
  return v + __builtin_bit_cast(float, t);
}

// ---------------------------------------------------------------------------
// Setup: one block per component k. Emits:
//  Wb: per-comp 4096 shorts in MAIN'S B-FRAGMENT ORDER — element B[kd][n]
//      (= -0.5*log2e*M[kd][n]) stored at
//      k*4096 + (((kd>>3)&3)*16 + (n&15))*64 + (kd>>5)*32 + (n>>4)*8 + (kd&7)
//      so main's lane reads its 64 shorts as 8 contiguous dwordx4.
//  cvec[k*64+i] = log2e * c_i ;  beta[k] = log2e*(beta+90).
//  Also zeroes ph[32768] and the done counter.
// ---------------------------------------------------------------------------
__global__ __launch_bounds__(256) void gmm_setup(
    const float* __restrict__ means_raw, const float* __restrict__ scale_raw,
    const float* __restrict__ weights_raw, unsigned short* __restrict__ Wb,
    float* __restrict__ cvec, float* __restrict__ beta,
    float* __restrict__ ph, unsigned int* __restrict__ done)
{
  const int k = blockIdx.x;
  const int t = threadIdx.x;
  const int lane = t & 63;
  const int wv = t >> 6;
  const int q = lane >> 4;
  const int jj = lane & 15;

  ph[k * 512 + t] = 0.0f;
  ph[k * 512 + 256 + t] = 0.0f;
  if (k == 0 && t == 0) *done = 0u;

  __shared__ float Plt[64][68];   // Plt[m][i] = L[i][m] for i>m, else 0
  __shared__ float Vt[64][68];    // Vt[c][m]  = Linv[m][c]
  __shared__ __align__(16) unsigned short Vb[64][72];  // bf16 Vt image
  __shared__ float dg[64], rdg[64], mu_s[64], y_s[64];

  {  // phase 1
    const int i = t >> 2;
    const int c0 = (t & 3) * 16;
    float4_ v4[4];
    const float4_* src = (const float4_*)(scale_raw + (size_t)k * 4096 + i * 64 + c0);
    v4[0] = src[0]; v4[1] = src[1]; v4[2] = src[2]; v4[3] = src[3];
#pragma unroll
    for (int e = 0; e < 16; ++e) {
      const int c = c0 + e;
      const float val = ((const float*)v4)[e] * (1.0f / 512.0f);
      Plt[c][i] = (c < i) ? val : 0.0f;
      if (c == i) { dg[i] = val; rdg[i] = __expf(-val); }
    }
  }
  if (t < 64) mu_s[t] = means_raw[k * 64 + t] * (1.0f / 64.0f);
  __syncthreads();

  // phase 2: forward substitution (col j = wv*16+jj, rows [16q,16q+16))
  {
    const int j = wv * 16 + jj;
    float s[16];
#pragma unroll
    for (int i = 0; i < 16; ++i) s[i] = 0.0f;
#pragma unroll
    for (int m = 0; m < 64; ++m) {
      const float rm = rdg[m];
      float vcand = (m == j) ? rm : -s[m & 15] * rm;
      const float v = __shfl(vcand, (m >> 4) * 16 + jj, 64);
      if (q == (m >> 4)) {
        Vt[j][m] = v;
        Vb[j][m] = f2bf(v);
      }
      const float4_* prow = (const float4_*)&Plt[m][16 * q];
      const float4_ p0 = prow[0], p1 = prow[1], p2 = prow[2], p3 = prow[3];
      s[0]  += p0[0] * v; s[1]  += p0[1] * v; s[2]  += p0[2] * v; s[3]  += p0[3] * v;
      s[4]  += p1[0] * v; s[5]  += p1[1] * v; s[6]  += p1[2] * v; s[7]  += p1[3] * v;
      s[8]  += p2[0] * v; s[9]  += p2[1] * v; s[10] += p2[2] * v; s[11] += p2[3] * v;
      s[12] += p3[0] * v; s[13] += p3[1] * v; s[14] += p3[2] * v; s[15] += p3[3] * v;
    }
  }
  __syncthreads();

  // phase 3a: M = V^T V via MFMA; scatter -0.5*log2e*M into B-frag image
  {
    const short8 a0 = *(const short8*)&Vb[16 * wv + jj][8 * q];
    const short8 a1 = *(const short8*)&Vb[16 * wv + jj][8 * q + 32];
#pragma unroll
    for (int t4 = 0; t4 < 4; ++t4) {
      const short8 b0 = *(const short8*)&Vb[jj + 16 * t4][8 * q];
      const short8 b1 = *(const short8*)&Vb[jj + 16 * t4][8 * q + 32];
      float4_ f = {0.f, 0.f, 0.f, 0.f};
      f = __builtin_amdgcn_mfma_f32_16x16x32_bf16(a0, b0, f, 0, 0, 0);
      f = __builtin_amdgcn_mfma_f32_16x16x32_bf16(a1, b1, f, 0, 0, 0);
#pragma unroll
      for (int r = 0; r < 4; ++r) {
        const int kd = 16 * wv + 4 * q + r;       // M row (= kdim, symmetric)
        const int n  = jj + 16 * t4;              // M col (= n)
        const int addr = k * 4096 + (((kd >> 3) & 3) * 16 + (n & 15)) * 64
                       + (kd >> 5) * 32 + (n >> 4) * 8 + (kd & 7);
        Wb[addr] = f2bf(-0.5f * LOG2E * f[r]);
      }
    }
  }
  if (wv == 0) {  // y = V*mu
    float acc = 0.0f;
    for (int j2 = 0; j2 < 64; ++j2) acc += Vt[j2][lane] * mu_s[j2];
    y_s[lane] = acc;
  }
  __syncthreads();

  // tail: c' = log2e * V^T y, beta' = log2e*(beta+90)
  if (t < 64) {
    const int i = t;
    float ci = 0.0f;
#pragma unroll
    for (int m4 = 0; m4 < 16; ++m4) {
      const float4_ a4 = *(const float4_*)&Vt[i][4 * m4];
      const float4_ b4 = *(const float4_*)&y_s[4 * m4];
      ci += a4[0] * b4[0] + a4[1] * b4[1] + a4[2] * b4[2] + a4[3] * b4[3];
    }
    cvec[k * 64 + i] = LOG2E * ci;
    float rq  = ci * mu_s[i];
    float dgv = dg[i];
    const float wr = weights_raw[i] * 0.125f;
    float mx = wr;
#pragma unroll
    for (int d = 1; d < 64; d <<= 1) mx = fmaxf(mx, __shfl_xor(mx, d, 64));
    float se = __expf(wr - mx);
#pragma unroll
    for (int d = 1; d < 64; d <<= 1) {
      se  += __shfl_xor(se, d, 64);
      rq  += __shfl_xor(rq, d, 64);
      dgv += __shfl_xor(dgv, d, 64);
    }
    if (i == 0) {
      const float wrk  = weights_raw[k] * 0.125f;
      const float logw = wrk - mx - __logf(se);
      const float bval = -0.5f * rq - 32.0f * LOG_2PI - dgv + logw;
      beta[k] = LOG2E * (bval + 90.0f);
    }
  }
}

// ---------------------------------------------------------------------------
// Main: 2048 blocks x 512 threads (8 waves). kh = &7, rt = >>3 (128 rows).
// Wave w owns comp k = kh*8+w: B-frags in REGISTERS (8 dwordx4, loaded once).
// Block stages x-tile once: bf16 A-frag image (16 KB) + bf16 col-major xc
// image (stride 20, 20.5 KB). Loop over 8 m-tiles: NO barriers, NO staging.
// Row exp-sums: ds_add_f32 into rowacc, then 1 global atomicAdd per row.
// Fused last-block tail computes -mean(log(ph)-90).
// ---------------------------------------------------------------------------
__global__ __launch_bounds__(512) __attribute__((amdgpu_waves_per_eu(4, 4)))
void gmm_main(
    const float* __restrict__ x, const unsigned short* __restrict__ Wb,
    const float* __restrict__ cvec, const float* __restrict__ beta,
    float* __restrict__ ph, unsigned int* __restrict__ done,
    float* __restrict__ out)
{
  __shared__ __align__(16) unsigned short Ai[8192];    // A-frag image, 16 KB
  __shared__ __align__(16) unsigned short Xc[10240];   // xc col-major s20, 20.5 KB
  __shared__ float rowacc[128];
  __shared__ int lastFlag;
  __shared__ float s8[8];

  const int t = threadIdx.x;        // 0..511
  const int lane = t & 63;
  const int wv = t >> 6;            // 0..7
  const int q = lane >> 4;
  const int lr = lane & 15;
  const int kh = blockIdx.x & 7;
  const int rt = blockIdx.x >> 3;
  const int rowBase = rt * 128;
  const int k = kh * 8 + wv;

  // ---- staging: thread t covers row rl = t>>2, 16 cols seg*16.. ----
  {
    const int rl = t >> 2;
    const int seg = t & 3;
    const int mtile = rl >> 4;
    const int mr = rl & 15;
    const float4_* src = (const float4_*)(x + (size_t)(rowBase + rl) * 64 + seg * 16);
    const float4_ v0 = src[0], v1 = src[1], v2 = src[2], v3 = src[3];
    unsigned short h[16];
#pragma unroll
    for (int e = 0; e < 4; ++e) {
      h[e]      = f2bf(v0[e]);
      h[4 + e]  = f2bf(v1[e]);
      h[8 + e]  = f2bf(v2[e]);
      h[12 + e] = f2bf(v3[e]);
    }
    // A-frag image: octets o0,o1; ks = seg>>1; lane = o*16+mr; 16 shorts/lane/mtile
    const int o0 = (2 * seg) & 3, o1 = (2 * seg + 1) & 3;
    const int ks = seg >> 1;
    short8 p0, p1;
#pragma unroll
    for (int e = 0; e < 8; ++e) { p0[e] = (short)h[e]; p1[e] = (short)h[8 + e]; }
    *(short8*)&Ai[mtile * 1024 + (o0 * 16 + mr) * 16 + ks * 8] = p0;
    *(short8*)&Ai[mtile * 1024 + (o1 * 16 + mr) * 16 + ks * 8] = p1;
    // xc image: [col][mr], col stride 20 shorts
#pragma unroll
    for (int e = 0; e < 16; ++e)
      Xc[mtile * 1280 + (seg * 16 + e) * 20 + mr] = h[e];
    if (t < 128) rowacc[t] = 0.0f;
  }

  // ---- wave init: B-frags + c + beta (once per wave) ----
  short8 b[2][4];
  {
    const unsigned short* wg = Wb + (size_t)k * 4096 + lane * 64;
#pragma unroll
    for (int ks = 0; ks < 2; ++ks)
#pragma unroll
      for (int t4 = 0; t4 < 4; ++t4)
        b[ks][t4] = *(const short8*)(wg + ks * 32 + t4 * 8);
  }
  float cc[4];
#pragma unroll
  for (int t4 = 0; t4 < 4; ++t4) cc[t4] = cvec[k * 64 + lr + 16 * t4];
  const float bk = beta[k];

  __syncthreads();

  // ---- main loop: 8 m-tiles, no barriers ----
#pragma unroll 2
  for (int mtile = 0; mtile < 8; ++mtile) {
    const short8 a0 = *(const short8*)&Ai[mtile * 1024 + lane * 16];
    const short8 a1 = *(const short8*)&Ai[mtile * 1024 + lane * 16 + 8];
    uint2_ xq[4];
#pragma unroll
    for (int t4 = 0; t4 < 4; ++t4)
      xq[t4] = *(const uint2_*)&Xc[mtile * 1280 + (lr + 16 * t4) * 20 + 4 * q];

    float4_ f[4];
#pragma unroll
    for (int t4 = 0; t4 < 4; ++t4) {
      const float cv = cc[t4];
      float4_ acc = {cv, cv, cv, cv};
      acc = __builtin_amdgcn_mfma_f32_16x16x32_bf16(a0, b[0][t4], acc, 0, 0, 0);
      acc = __builtin_amdgcn_mfma_f32_16x16x32_bf16(a1, b[1][t4], acc, 0, 0, 0);
      f[t4] = acc;
    }

    float xr[4][4];
#pragma unroll
    for (int t4 = 0; t4 < 4; ++t4) {
      xr[t4][0] = lo2f(xq[t4][0]);
      xr[t4][1] = hi2f(xq[t4][0]);
      xr[t4][2] = lo2f(xq[t4][1]);
      xr[t4][3] = hi2f(xq[t4][1]);
    }
    float ev[4];
#pragma unroll
    for (int r = 0; r < 4; ++r) {
      float sdot = xr[0][r] * f[0][r] + xr[1][r] * f[1][r]
                 + xr[2][r] * f[2][r] + xr[3][r] * f[3][r];
      sdot = dpp_add<0x121>(sdot);  // row_ror:1
      sdot = dpp_add<0x122>(sdot);  // row_ror:2
      sdot = dpp_add<0x124>(sdot);  // row_ror:4
      sdot = dpp_add<0x128>(sdot);  // row_ror:8
      ev[r] = exp2f(sdot + bk);
    }
    if (lr == 0) {
#pragma unroll
      for (int r = 0; r < 4; ++r)
        atomicAdd(&rowacc[mtile * 16 + 4 * q + r], ev[r]);
    }
  }

  __syncthreads();
  if (t < 128) atomicAdd(&ph[rowBase + t], rowacc[t]);

  // ---- fused finalization: last block computes -mean(log(ph)-90) ----
  __threadfence();
  if (t == 0) lastFlag = (atomicAdd(done, 1u) == 2047u) ? 1 : 0;
  __syncthreads();
  if (lastFlag) {
    float v = 0.0f;
    for (int i = t; i < 32768; i += 512) {
      const float s = __hip_atomic_load(&ph[i], __ATOMIC_RELAXED, __HIP_MEMORY_SCOPE_AGENT);
      v += __logf(s) - 90.0f;
    }
#pragma unroll
    for (int d = 1; d < 64; d <<= 1) v += __shfl_xor(v, d, 64);
    if (lane == 0) s8[wv] = v;
    __syncthreads();
    if (t == 0) {
      float s = 0.0f;
#pragma unroll
      for (int w = 0; w < 8; ++w) s += s8[w];
      out[0] = -s * (1.0f / 32768.0f);
    }
  }
}

extern "C" void kernel_launch(void* const* d_in, const int* in_sizes, int n_in,
                              void* d_out, int out_size, void* d_ws, size_t ws_size,
                              hipStream_t stream)
{
  const float* x           = (const float*)d_in[0];  // [32768,64]
  const float* means_raw   = (const float*)d_in[1];  // [64,64]
  const float* scale_raw   = (const float*)d_in[2];  // [64,64,64]
  const float* weights_raw = (const float*)d_in[3];  // [64]
  float* out = (float*)d_out;

  char* ws = (char*)d_ws;
  unsigned short* Wb = (unsigned short*)ws;             // 64*4096*2 = 524288 B
  float* cvec        = (float*)(ws + 524288);           // 16384 B
  float* beta        = (float*)(ws + 540672);           // 256 B
  float* ph          = (float*)(ws + 540928);           // 131072 B
  unsigned int* done = (unsigned int*)(ws + 672000);    // 4 B

  gmm_setup<<<64, 256, 0, stream>>>(means_raw, scale_raw, weights_raw,
                                    Wb, cvec, beta, ph, done);
  gmm_main<<<2048, 512, 0, stream>>>(x, Wb, cvec, beta, ph, done, out);
}

// Round 8
// 109.007 us; speedup vs baseline: 3.3506x; 3.3506x over previous
//
#include <hip/hip_runtime.h>

// B=32768, K=64, D=64, GAIN=1.0
#define LOG_2PI 1.8378770664093453f
#define LOG2E   1.4426950408889634f

typedef __attribute__((ext_vector_type(8))) short  short8;   // 8 x bf16
typedef __attribute__((ext_vector_type(4))) float  float4_;
typedef __attribute__((ext_vector_type(2))) unsigned int uint2_;

__device__ __forceinline__ unsigned short f2bf(float f) {
  unsigned u = __builtin_bit_cast(unsigned, f);
  u += 0x7fffu + ((u >> 16) & 1u);   // RNE
  return (unsigned short)(u >> 16);
}
__device__ __forceinline__ float hi2f(unsigned u) {        // bf16 in high half
  return __builtin_bit_cast(float, u & 0xffff0000u);
}
__device__ __forceinline__ float lo2f(unsigned u) {        // bf16 in low half
  return __builtin_bit_cast(float, u << 16);
}
template <int CTRL>
__device__ __forceinline__ float dpp_add(float v) {
  int t = __builtin_amdgcn_mov_dpp(__builtin_bit_cast(int, v), CTRL, 0xf, 0xf, true);
  return v + __builtin_bit_cast(float, t);
}

// ---------------------------------------------------------------------------
// Setup: one block per component k. Emits:
//  Wb: per-comp 4096 shorts in MAIN'S B-FRAGMENT ORDER — element B[kd][n]
//      (= -0.5*log2e*M[kd][n]) stored at
//      k*4096 + (((kd>>3)&3)*16 + (n&15))*64 + (kd>>5)*32 + (n>>4)*8 + (kd&7)
//      so main's lane reads its 64 shorts as 8 contiguous dwordx4.
//  cvec[k*64+i] = log2e * c_i ;  beta[k] = log2e*(beta+90).
//  Also zeroes ph[32768] (fp32 row accumulators) and out[0].
// ---------------------------------------------------------------------------
__global__ __launch_bounds__(256) void gmm_setup(
    const float* __restrict__ means_raw, const float* __restrict__ scale_raw,
    const float* __restrict__ weights_raw, unsigned short* __restrict__ Wb,
    float* __restrict__ cvec, float* __restrict__ beta,
    float* __restrict__ ph, float* __restrict__ out)
{
  const int k = blockIdx.x;
  const int t = threadIdx.x;
  const int lane = t & 63;
  const int wv = t >> 6;
  const int q = lane >> 4;
  const int jj = lane & 15;

  ph[k * 512 + t] = 0.0f;
  ph[k * 512 + 256 + t] = 0.0f;
  if (k == 0 && t == 0) out[0] = 0.0f;

  __shared__ float Plt[64][68];   // Plt[m][i] = L[i][m] for i>m, else 0
  __shared__ float Vt[64][68];    // Vt[c][m]  = Linv[m][c]
  __shared__ __align__(16) unsigned short Vb[64][72];  // bf16 Vt image
  __shared__ float dg[64], rdg[64], mu_s[64], y_s[64];

  {  // phase 1
    const int i = t >> 2;
    const int c0 = (t & 3) * 16;
    float4_ v4[4];
    const float4_* src = (const float4_*)(scale_raw + (size_t)k * 4096 + i * 64 + c0);
    v4[0] = src[0]; v4[1] = src[1]; v4[2] = src[2]; v4[3] = src[3];
#pragma unroll
    for (int e = 0; e < 16; ++e) {
      const int c = c0 + e;
      const float val = ((const float*)v4)[e] * (1.0f / 512.0f);
      Plt[c][i] = (c < i) ? val : 0.0f;
      if (c == i) { dg[i] = val; rdg[i] = __expf(-val); }
    }
  }
  if (t < 64) mu_s[t] = means_raw[k * 64 + t] * (1.0f / 64.0f);
  __syncthreads();

  // phase 2: forward substitution (col j = wv*16+jj, rows [16q,16q+16))
  {
    const int j = wv * 16 + jj;
    float s[16];
#pragma unroll
    for (int i = 0; i < 16; ++i) s[i] = 0.0f;
#pragma unroll
    for (int m = 0; m < 64; ++m) {
      const float rm = rdg[m];
      float vcand = (m == j) ? rm : -s[m & 15] * rm;
      const float v = __shfl(vcand, (m >> 4) * 16 + jj, 64);
      if (q == (m >> 4)) {
        Vt[j][m] = v;
        Vb[j][m] = f2bf(v);
      }
      const float4_* prow = (const float4_*)&Plt[m][16 * q];
      const float4_ p0 = prow[0], p1 = prow[1], p2 = prow[2], p3 = prow[3];
      s[0]  += p0[0] * v; s[1]  += p0[1] * v; s[2]  += p0[2] * v; s[3]  += p0[3] * v;
      s[4]  += p1[0] * v; s[5]  += p1[1] * v; s[6]  += p1[2] * v; s[7]  += p1[3] * v;
      s[8]  += p2[0] * v; s[9]  += p2[1] * v; s[10] += p2[2] * v; s[11] += p2[3] * v;
      s[12] += p3[0] * v; s[13] += p3[1] * v; s[14] += p3[2] * v; s[15] += p3[3] * v;
    }
  }
  __syncthreads();

  // phase 3a: M = V^T V via MFMA; scatter -0.5*log2e*M into B-frag image
  {
    const short8 a0 = *(const short8*)&Vb[16 * wv + jj][8 * q];
    const short8 a1 = *(const short8*)&Vb[16 * wv + jj][8 * q + 32];
#pragma unroll
    for (int t4 = 0; t4 < 4; ++t4) {
      const short8 b0 = *(const short8*)&Vb[jj + 16 * t4][8 * q];
      const short8 b1 = *(const short8*)&Vb[jj + 16 * t4][8 * q + 32];
      float4_ f = {0.f, 0.f, 0.f, 0.f};
      f = __builtin_amdgcn_mfma_f32_16x16x32_bf16(a0, b0, f, 0, 0, 0);
      f = __builtin_amdgcn_mfma_f32_16x16x32_bf16(a1, b1, f, 0, 0, 0);
#pragma unroll
      for (int r = 0; r < 4; ++r) {
        const int kd = 16 * wv + 4 * q + r;       // M row (= kdim, symmetric)
        const int n  = jj + 16 * t4;              // M col (= n)
        const int addr = k * 4096 + (((kd >> 3) & 3) * 16 + (n & 15)) * 64
                       + (kd >> 5) * 32 + (n >> 4) * 8 + (kd & 7);
        Wb[addr] = f2bf(-0.5f * LOG2E * f[r]);
      }
    }
  }
  if (wv == 0) {  // y = V*mu
    float acc = 0.0f;
    for (int j2 = 0; j2 < 64; ++j2) acc += Vt[j2][lane] * mu_s[j2];
    y_s[lane] = acc;
  }
  __syncthreads();

  // tail: c' = log2e * V^T y, beta' = log2e*(beta+90)
  if (t < 64) {
    const int i = t;
    float ci = 0.0f;
#pragma unroll
    for (int m4 = 0; m4 < 16; ++m4) {
      const float4_ a4 = *(const float4_*)&Vt[i][4 * m4];
      const float4_ b4 = *(const float4_*)&y_s[4 * m4];
      ci += a4[0] * b4[0] + a4[1] * b4[1] + a4[2] * b4[2] + a4[3] * b4[3];
    }
    cvec[k * 64 + i] = LOG2E * ci;
    float rq  = ci * mu_s[i];
    float dgv = dg[i];
    const float wr = weights_raw[i] * 0.125f;
    float mx = wr;
#pragma unroll
    for (int d = 1; d < 64; d <<= 1) mx = fmaxf(mx, __shfl_xor(mx, d, 64));
    float se = __expf(wr - mx);
#pragma unroll
    for (int d = 1; d < 64; d <<= 1) {
      se  += __shfl_xor(se, d, 64);
      rq  += __shfl_xor(rq, d, 64);
      dgv += __shfl_xor(dgv, d, 64);
    }
    if (i == 0) {
      const float wrk  = weights_raw[k] * 0.125f;
      const float logw = wrk - mx - __logf(se);
      const float bval = -0.5f * rq - 32.0f * LOG_2PI - dgv + logw;
      beta[k] = LOG2E * (bval + 90.0f);
    }
  }
}

// ---------------------------------------------------------------------------
// Main: 2048 blocks x 512 threads (8 waves). kh = &7, rt = >>3 (128 rows).
// Wave w owns comp k = kh*8+w: B-frags resident in registers/AGPRs (8
// dwordx4, loaded once). Block stages x-tile once (bf16 A-frag image 16 KB +
// bf16 col-major xc image 20.5 KB). 8 m-tiles: no in-loop barriers/staging.
// Tail: LDS rowacc -> one global atomicAdd per row. NO __threadfence / done
// counter (R6/R7 post-mortem: per-block agent-scope fence on 8-XCD MI355X
// cost ~300 us — finalization is a separate dispatch instead).
// ---------------------------------------------------------------------------
__global__ __launch_bounds__(512) __attribute__((amdgpu_waves_per_eu(4, 4)))
void gmm_main(
    const float* __restrict__ x, const unsigned short* __restrict__ Wb,
    const float* __restrict__ cvec, const float* __restrict__ beta,
    float* __restrict__ ph)
{
  __shared__ __align__(16) unsigned short Ai[8192];    // A-frag image, 16 KB
  __shared__ __align__(16) unsigned short Xc[10240];   // xc col-major s20, 20.5 KB
  __shared__ float rowacc[128];

  const int t = threadIdx.x;        // 0..511
  const int lane = t & 63;
  const int wv = t >> 6;            // 0..7
  const int q = lane >> 4;
  const int lr = lane & 15;
  const int kh = blockIdx.x & 7;
  const int rt = blockIdx.x >> 3;
  const int rowBase = rt * 128;
  const int k = kh * 8 + wv;

  // ---- staging: thread t covers row rl = t>>2, 16 cols seg*16.. ----
  {
    const int rl = t >> 2;
    const int seg = t & 3;
    const int mtile = rl >> 4;
    const int mr = rl & 15;
    const float4_* src = (const float4_*)(x + (size_t)(rowBase + rl) * 64 + seg * 16);
    const float4_ v0 = src[0], v1 = src[1], v2 = src[2], v3 = src[3];
    unsigned short h[16];
#pragma unroll
    for (int e = 0; e < 4; ++e) {
      h[e]      = f2bf(v0[e]);
      h[4 + e]  = f2bf(v1[e]);
      h[8 + e]  = f2bf(v2[e]);
      h[12 + e] = f2bf(v3[e]);
    }
    // A-frag image: octets o0,o1; ks = seg>>1; lane = o*16+mr
    const int o0 = (2 * seg) & 3, o1 = (2 * seg + 1) & 3;
    const int ks = seg >> 1;
    short8 p0, p1;
#pragma unroll
    for (int e = 0; e < 8; ++e) { p0[e] = (short)h[e]; p1[e] = (short)h[8 + e]; }
    *(short8*)&Ai[mtile * 1024 + (o0 * 16 + mr) * 16 + ks * 8] = p0;
    *(short8*)&Ai[mtile * 1024 + (o1 * 16 + mr) * 16 + ks * 8] = p1;
    // xc image: [col][mr], col stride 20 shorts
#pragma unroll
    for (int e = 0; e < 16; ++e)
      Xc[mtile * 1280 + (seg * 16 + e) * 20 + mr] = h[e];
    if (t < 128) rowacc[t] = 0.0f;
  }

  // ---- wave init: B-frags + c + beta (once per wave) ----
  short8 b[2][4];
  {
    const unsigned short* wg = Wb + (size_t)k * 4096 + lane * 64;
#pragma unroll
    for (int ks = 0; ks < 2; ++ks)
#pragma unroll
      for (int t4 = 0; t4 < 4; ++t4)
        b[ks][t4] = *(const short8*)(wg + ks * 32 + t4 * 8);
  }
  float cc[4];
#pragma unroll
  for (int t4 = 0; t4 < 4; ++t4) cc[t4] = cvec[k * 64 + lr + 16 * t4];
  const float bk = beta[k];

  __syncthreads();

  // ---- main loop: 8 m-tiles, no barriers ----
#pragma unroll 2
  for (int mtile = 0; mtile < 8; ++mtile) {
    const short8 a0 = *(const short8*)&Ai[mtile * 1024 + lane * 16];
    const short8 a1 = *(const short8*)&Ai[mtile * 1024 + lane * 16 + 8];
    uint2_ xq[4];
#pragma unroll
    for (int t4 = 0; t4 < 4; ++t4)
      xq[t4] = *(const uint2_*)&Xc[mtile * 1280 + (lr + 16 * t4) * 20 + 4 * q];

    float4_ f[4];
#pragma unroll
    for (int t4 = 0; t4 < 4; ++t4) {
      const float cv = cc[t4];
      float4_ acc = {cv, cv, cv, cv};
      acc = __builtin_amdgcn_mfma_f32_16x16x32_bf16(a0, b[0][t4], acc, 0, 0, 0);
      acc = __builtin_amdgcn_mfma_f32_16x16x32_bf16(a1, b[1][t4], acc, 0, 0, 0);
      f[t4] = acc;
    }

    float xr[4][4];
#pragma unroll
    for (int t4 = 0; t4 < 4; ++t4) {
      xr[t4][0] = lo2f(xq[t4][0]);
      xr[t4][1] = hi2f(xq[t4][0]);
      xr[t4][2] = lo2f(xq[t4][1]);
      xr[t4][3] = hi2f(xq[t4][1]);
    }
    float ev[4];
#pragma unroll
    for (int r = 0; r < 4; ++r) {
      float sdot = xr[0][r] * f[0][r] + xr[1][r] * f[1][r]
                 + xr[2][r] * f[2][r] + xr[3][r] * f[3][r];
      sdot = dpp_add<0x121>(sdot);  // row_ror:1
      sdot = dpp_add<0x122>(sdot);  // row_ror:2
      sdot = dpp_add<0x124>(sdot);  // row_ror:4
      sdot = dpp_add<0x128>(sdot);  // row_ror:8
      ev[r] = exp2f(sdot + bk);
    }
    if (lr == 0) {
#pragma unroll
      for (int r = 0; r < 4; ++r)
        atomicAdd(&rowacc[mtile * 16 + 4 * q + r], ev[r]);
    }
  }

  __syncthreads();
  if (t < 128) atomicAdd(&ph[rowBase + t], rowacc[t]);
}

// ---------------------------------------------------------------------------
__global__ __launch_bounds__(256) void gmm_final(const float* __restrict__ ph,
                                                 float* __restrict__ out)
{
  const int t = threadIdx.x;
  const int r0 = blockIdx.x * 512 + t;
  float v = (__logf(ph[r0]) - 90.0f) + (__logf(ph[r0 + 256]) - 90.0f);
#pragma unroll
  for (int d = 1; d < 64; d <<= 1) v += __shfl_xor(v, d, 64);
  __shared__ float s4[4];
  if ((t & 63) == 0) s4[t >> 6] = v;
  __syncthreads();
  if (t == 0)
    atomicAdd(out, -(s4[0] + s4[1] + s4[2] + s4[3]) * (1.0f / 32768.0f));
}

extern "C" void kernel_launch(void* const* d_in, const int* in_sizes, int n_in,
                              void* d_out, int out_size, void* d_ws, size_t ws_size,
                              hipStream_t stream)
{
  const float* x           = (const float*)d_in[0];  // [32768,64]
  const float* means_raw   = (const float*)d_in[1];  // [64,64]
  const float* scale_raw   = (const float*)d_in[2];  // [64,64,64]
  const float* weights_raw = (const float*)d_in[3];  // [64]
  float* out = (float*)d_out;

  char* ws = (char*)d_ws;
  unsigned short* Wb = (unsigned short*)ws;             // 64*4096*2 = 524288 B
  float* cvec        = (float*)(ws + 524288);           // 16384 B
  float* beta        = (float*)(ws + 540672);           // 256 B
  float* ph          = (float*)(ws + 540928);           // 131072 B

  gmm_setup<<<64, 256, 0, stream>>>(means_raw, scale_raw, weights_raw,
                                    Wb, cvec, beta, ph, out);
  gmm_main<<<2048, 512, 0, stream>>>(x, Wb, cvec, beta, ph);
  gmm_final<<<64, 256, 0, stream>>>(ph, out);
}